// Round 8
// baseline (282.324 us; speedup 1.0000x reference)
//
#include <hip/hip_runtime.h>
#include <math.h>

#define DIMC 192
#define INNER 768
#define NEXP 8
#define NB 4
#define HH 64
#define WW 64
#define PPI 4096
#define NPIX 16384
#define MAXROWS 33792   // 264 * 128

typedef __attribute__((ext_vector_type(8))) short bf16x8;
typedef __attribute__((ext_vector_type(4))) float f32x4;

static __device__ __forceinline__ float bf2f(short s) {
  union { unsigned int u; float f; } v;
  v.u = ((unsigned int)(unsigned short)s) << 16;
  return v.f;
}
static __device__ __forceinline__ short f2bf(float f) {
  union { float f; unsigned int u; } v; v.f = f;
  unsigned int r = v.u + 0x7fffu + ((v.u >> 16) & 1u);
  return (short)(r >> 16);
}
static __device__ __forceinline__ unsigned int pk2(float a, float b) {
  return (unsigned int)(unsigned short)f2bf(a)
       | ((unsigned int)(unsigned short)f2bf(b) << 16);
}
static __device__ __forceinline__ void gl2lds16(const void* g, void* l) {
  __builtin_amdgcn_global_load_lds(
      (const __attribute__((address_space(1))) void*)g,
      (__attribute__((address_space(3))) void*)l, 16, 0, 0);
}

// ---------------- prep: fold LN gamma/beta into W1/b1, cast to bf16 ----------
__global__ __launch_bounds__(192) void k_prep_w1(const float* __restrict__ w1,
                                                 const float* __restrict__ b1,
                                                 const float* __restrict__ lng,
                                                 const float* __restrict__ lnb,
                                                 short* __restrict__ w1p,
                                                 float* __restrict__ b1p) {
  const int i = blockIdx.x;
  const int e = blockIdx.y;
  const int c = threadIdx.x;
  const size_t base = ((size_t)e*INNER + i)*DIMC;
  float w = w1[base + c];
  float g = lng[e*DIMC + c];
  float bb = lnb[e*DIMC + c];
  w1p[base + c] = f2bf(w * g);
  float r = w * bb;
  #pragma unroll
  for (int off = 32; off >= 1; off >>= 1) r += __shfl_down(r, off);
  __shared__ float part[3];
  const int lane = threadIdx.x & 63, wv = threadIdx.x >> 6;
  if (lane == 0) part[wv] = r;
  __syncthreads();
  if (threadIdx.x == 0)
    b1p[e*INNER + i] = b1[e*INNER + i] + part[0] + part[1] + part[2];
}

__global__ __launch_bounds__(256) void k_prep_w2(const float* __restrict__ w2,
                                                 short* __restrict__ w2b, int n) {
  int idx = (blockIdx.x*256 + threadIdx.x)*4;
  if (idx + 3 < n) {
    float4 v = *(const float4*)(w2 + idx);
    short4 o; o.x = f2bf(v.x); o.y = f2bf(v.y); o.z = f2bf(v.z); o.w = f2bf(v.w);
    *(short4*)(w2b + idx) = o;
  } else {
    for (int k = idx; k < n; ++k) w2b[k] = f2bf(w2[k]);
  }
}

// ---------------- gate + layernorm -> nx, (e0,e1), (w0,w1) -------------------
__global__ __launch_bounds__(256) void k_gate(const float* __restrict__ x,
                                              const float* __restrict__ wg,
                                              const float* __restrict__ bg,
                                              short* __restrict__ nx,
                                              int* __restrict__ e01,
                                              float2* __restrict__ w01) {
  __shared__ float swg[NEXP][DIMC];
  __shared__ float sbg[NEXP];
  __shared__ float red[10][4][64];
  __shared__ float smr[2][64];
  const int t = threadIdx.x;
  for (int k = t; k < NEXP*DIMC; k += 256) swg[k/DIMC][k%DIMC] = wg[k];
  if (t < NEXP) sbg[t] = bg[t];
  __syncthreads();
  const int n0 = blockIdx.x * 64;
  const int b = n0 >> 12;
  const int p0 = n0 & 4095;
  const int l = t & 63, w = t >> 6;
  const float* xp = x + (size_t)b*DIMC*PPI + p0 + l;
  float xr[48];
  float sum = 0.f, ssq = 0.f;
  float lg[NEXP] = {0,0,0,0,0,0,0,0};
  #pragma unroll
  for (int k = 0; k < 48; ++k) {
    const int c = w*48 + k;
    float xv = xp[(size_t)c*PPI];
    xr[k] = xv;
    sum += xv; ssq += xv*xv;
    #pragma unroll
    for (int e = 0; e < NEXP; ++e) lg[e] += xv * swg[e][c];
  }
  red[0][w][l] = sum;
  red[1][w][l] = ssq;
  #pragma unroll
  for (int e = 0; e < NEXP; ++e) red[2+e][w][l] = lg[e];
  __syncthreads();
  if (t < 64) {
    float ts = red[0][0][l] + red[0][1][l] + red[0][2][l] + red[0][3][l];
    float tq = red[1][0][l] + red[1][1][l] + red[1][2][l] + red[1][3][l];
    float lgt[NEXP];
    #pragma unroll
    for (int e = 0; e < NEXP; ++e)
      lgt[e] = red[2+e][0][l] + red[2+e][1][l] + red[2+e][2][l] + red[2+e][3][l] + sbg[e];
    const float mean = ts * (1.0f/DIMC);
    const float var  = tq * (1.0f/DIMC) - mean*mean;
    const float rstd = rsqrtf(var + 1e-5f);
    smr[0][l] = mean; smr[1][l] = rstd;
    int e0 = 0; float l0 = lgt[0];
    #pragma unroll
    for (int e = 1; e < NEXP; ++e) if (lgt[e] > l0) { l0 = lgt[e]; e0 = e; }
    int e1 = -1; float l1 = -1e30f;
    #pragma unroll
    for (int e = 0; e < NEXP; ++e) if (e != e0 && lgt[e] > l1) { l1 = lgt[e]; e1 = e; }
    const float ex = expf(l1 - l0);
    const float w0 = 1.0f/(1.0f + ex);
    const float w1v = ex * w0;
    e01[n0 + l] = e0 | (e1 << 8);
    w01[n0 + l] = make_float2(w0, w1v);
  }
  __syncthreads();
  const float mean = smr[0][l], rstd = smr[1][l];
  short* nrow = nx + (size_t)(n0 + l)*DIMC + w*48;
  #pragma unroll
  for (int q = 0; q < 6; ++q) {
    bf16x8 v;
    #pragma unroll
    for (int j = 0; j < 8; ++j)
      v[j] = f2bf((xr[q*8 + j] - mean) * rstd);
    *(bf16x8*)(nrow + q*8) = v;
  }
}

// ---------------- routing pass 1: per-(expert, 256px-block) counts -----------
__global__ __launch_bounds__(256) void k_route1(const int* __restrict__ e01,
                                                int* __restrict__ cnt) {
  __shared__ int wc[NEXP][4];
  const int t = threadIdx.x;
  const int n = blockIdx.x*256 + t;
  const int ee = e01[n];
  const int e0 = ee & 0xff, e1 = (ee >> 8) & 0xff;
  const int lane = t & 63, wv = t >> 6;
  #pragma unroll
  for (int e = 0; e < NEXP; ++e) {
    unsigned long long m = __ballot(e0 == e || e1 == e);
    if (lane == 0) wc[e][wv] = __popcll(m);
  }
  __syncthreads();
  if (t < NEXP) cnt[t*64 + blockIdx.x] = wc[t][0] + wc[t][1] + wc[t][2] + wc[t][3];
}

// ---------------- routing pass 2: serial scan -> offsets, segments -----------
__global__ void k_route2(const int* __restrict__ cnt, int* __restrict__ off,
                         int* __restrict__ seg) {
  if (threadIdx.x != 0 || blockIdx.x != 0) return;
  int start = 0;
  for (int e = 0; e < NEXP; ++e) {
    int run = start;
    for (int b = 0; b < 64; ++b) { off[e*64 + b] = run; run += cnt[e*64 + b]; }
    int m = run - start;
    int pad = (m + 127) & ~127;
    seg[e*3 + 0] = start;
    seg[e*3 + 1] = m;
    seg[e*3 + 2] = start + pad;
    start += pad;
  }
  seg[24] = start;  // total padded rows
}

// -------- routing pass 3: slots (dense->compact), j0/j1, slot->pixel --------
__global__ __launch_bounds__(256) void k_route3(const int* __restrict__ e01,
                                                const int* __restrict__ off,
                                                int* __restrict__ slot,
                                                int* __restrict__ j0a,
                                                int* __restrict__ j1a,
                                                int* __restrict__ pix) {
  __shared__ int wc[NEXP][4];
  const int t = threadIdx.x;
  const int n = blockIdx.x*256 + t;
  const int ee = e01[n];
  const int e0 = ee & 0xff, e1 = (ee >> 8) & 0xff;
  const int lane = t & 63, wv = t >> 6;
  unsigned long long masks[NEXP];
  #pragma unroll
  for (int e = 0; e < NEXP; ++e) {
    unsigned long long m = __ballot(e0 == e || e1 == e);
    if (lane == 0) wc[e][wv] = __popcll(m);
    masks[e] = m;
  }
  __syncthreads();
  int j0 = 0, j1 = 0;
  #pragma unroll
  for (int e = 0; e < NEXP; ++e) {
    int base = off[e*64 + blockIdx.x];
    #pragma unroll
    for (int w = 0; w < 4; ++w) if (w < wv) base += wc[e][w];
    int rank = __popcll(masks[e] & ((1ull << lane) - 1ull));
    bool sel = (e0 == e || e1 == e);
    int j = base + rank;
    slot[(size_t)e*NPIX + n] = sel ? j : -1;
    if (sel) pix[j] = n;
    if (e == e0) j0 = j;
    if (e == e1) j1 = j;
  }
  j0a[n] = j0; j1a[n] = j1;
}

// ---------------- zero gTc padding rows --------------------------------------
__global__ __launch_bounds__(256) void k_padzero(const int* __restrict__ seg,
                                                 short* __restrict__ gTc) {
  const int e = blockIdx.x;
  const int start = seg[e*3], m = seg[e*3+1], pend = seg[e*3+2];
  const size_t base = (size_t)(start + m) * INNER;
  const size_t n = (size_t)(pend - start - m) * INNER;
  for (size_t i = threadIdx.x; i < n; i += 256) gTc[base + i] = 0;
}

// ------- up-projection GEMM: 128x128, BK=64, XOR-swizzled LDS;
// ------- epilogue: LDS transpose -> hT[n][768] coalesced 16B stores ----------
__global__ __launch_bounds__(256) void k_up(const short* __restrict__ w1p,
                                            const float* __restrict__ b1p,
                                            const short* __restrict__ nx,
                                            short* __restrict__ hbuf, int eb) {
  __shared__ alignas(16) short smemU[128*136];   // As|Bs during GEMM, TT after
  short* As = smemU;
  short* Bs = smemU + 128*64;
  const int el = blockIdx.z;
  const int e = eb + el;
  const short* A = w1p + (size_t)e*INNER*DIMC;
  short* H = hbuf + (size_t)el*NPIX*INNER;      // hT layout [n][768]
  const int n0 = blockIdx.x << 7;
  const int i0 = blockIdx.y << 7;
  const int t = threadIdx.x;
  const int wv = t >> 6, lane = t & 63;
  const int wm = (wv & 1) << 6;
  const int wn = (wv >> 1) << 6;
  const int r15 = lane & 15, kg = lane >> 4;
  f32x4 acc[4][4] = {};
  for (int k0 = 0; k0 < DIMC; k0 += 64) {
    __syncthreads();
    #pragma unroll
    for (int q = 0; q < 4; ++q) {
      const int c = q*256 + t;
      const int row = c >> 3;
      const int kb = ((c & 7) << 4) ^ ((row & 7) << 4);   // pre-swizzled source
      gl2lds16(A + (size_t)(i0 + row)*DIMC + k0 + (kb >> 1), (char*)As + c*16);
      gl2lds16(nx + (size_t)(n0 + row)*DIMC + k0 + (kb >> 1), (char*)Bs + c*16);
    }
    __syncthreads();
    #pragma unroll
    for (int ks = 0; ks < 2; ++ks) {
      bf16x8 af[4], bfr[4];
      #pragma unroll
      for (int mf = 0; mf < 4; ++mf) {
        const int row = wm + mf*16 + r15;
        const int kb = (ks*64 + kg*16) ^ ((row & 7) << 4);
        af[mf] = *(const bf16x8*)((const char*)As + row*128 + kb);
      }
      #pragma unroll
      for (int nf = 0; nf < 4; ++nf) {
        const int row = wn + nf*16 + r15;
        const int kb = (ks*64 + kg*16) ^ ((row & 7) << 4);
        bfr[nf] = *(const bf16x8*)((const char*)Bs + row*128 + kb);
      }
      #pragma unroll
      for (int mf = 0; mf < 4; ++mf)
        #pragma unroll
        for (int nf = 0; nf < 4; ++nf)
          acc[mf][nf] = __builtin_amdgcn_mfma_f32_16x16x32_bf16(af[mf], bfr[nf], acc[mf][nf], 0, 0, 0);
    }
  }
  // epilogue: acc(+bias) -> TT[n_l][i_l] (stride 136 shorts, 16B-aligned rows)
  __syncthreads();
  unsigned int* TT32 = (unsigned int*)smemU;
  const float* b1e = b1p + e*INNER + i0;
  #pragma unroll
  for (int mf = 0; mf < 4; ++mf) {
    const int ib = wm + mf*16 + (kg << 2);
    float bias[4];
    #pragma unroll
    for (int r = 0; r < 4; ++r) bias[r] = b1e[ib + r];
    #pragma unroll
    for (int nf = 0; nf < 4; ++nf) {
      const int nl = wn + nf*16 + r15;
      TT32[nl*68 + (ib >> 1)]     = pk2(acc[mf][nf][0] + bias[0], acc[mf][nf][1] + bias[1]);
      TT32[nl*68 + (ib >> 1) + 1] = pk2(acc[mf][nf][2] + bias[2], acc[mf][nf][3] + bias[3]);
    }
  }
  __syncthreads();
  const short* TT = smemU;
  #pragma unroll
  for (int s = 0; s < 8; ++s) {
    const int idx = (s << 8) + t;
    const int nl = idx >> 4, cg = idx & 15;
    bf16x8 v = *(const bf16x8*)(TT + nl*136 + cg*8);
    *(bf16x8*)(H + (size_t)(n0 + nl)*INNER + i0 + cg*8) = v;
  }
}

// ------- sparse depthwise 3x3 + GELU over routed slots only, barrier-free ----
// thread = (slot, channel-pair); taps read hT[n'][ch] coalesced across ch-lanes
__global__ __launch_bounds__(256) void k_dws(const short* __restrict__ hbuf,
                                             const float* __restrict__ dw,
                                             const float* __restrict__ bdw,
                                             const int* __restrict__ pix,
                                             const int* __restrict__ seg,
                                             short* __restrict__ gTc,
                                             int eb, int ne) {
  const int j0 = blockIdx.x << 3;     // 8 slots per block
  if (j0 >= seg[24]) return;
  int e = 0;
  #pragma unroll
  for (int q = 0; q < NEXP; ++q)
    if (j0 >= seg[q*3] && j0 < seg[q*3+2]) e = q;
  if (e < eb || e >= eb + ne) return;
  const int t = threadIdx.x;
  const int sl = t >> 5, cp = t & 31;
  const int j = j0 + sl;
  if (j >= seg[e*3] + seg[e*3+1]) return;   // padding slot (gTc zeroed elsewhere)
  const int ch = (blockIdx.y << 6) + (cp << 1);
  const int n = pix[j];
  const int p = n & 4095, y = p >> 6, x = p & 63;
  const short* hb = hbuf + (size_t)(e - eb)*NPIX*INNER;
  const float* dwp = dw + ((size_t)e*INNER + ch)*9;
  float k0[9], k1[9];
  #pragma unroll
  for (int q = 0; q < 9; ++q) { k0[q] = dwp[q]; k1[q] = dwp[9 + q]; }
  float a0 = bdw[e*INNER + ch], a1 = bdw[e*INNER + ch + 1];
  #pragma unroll
  for (int dy = 0; dy < 3; ++dy) {
    const int yy = y + dy - 1;
    if (yy < 0 || yy > 63) continue;
    #pragma unroll
    for (int dx = 0; dx < 3; ++dx) {
      const int xx = x + dx - 1;
      if (xx < 0 || xx > 63) continue;
      const unsigned int v = *(const unsigned int*)
          (hb + (size_t)(n + (dy - 1)*64 + (dx - 1))*INNER + ch);
      a0 += k0[dy*3 + dx] * bf2f((short)(v & 0xffff));
      a1 += k1[dy*3 + dx] * bf2f((short)(v >> 16));
    }
  }
  const float g0 = 0.5f*a0*(1.0f + erff(a0*0.70710678118654752f));
  const float g1 = 0.5f*a1*(1.0f + erff(a1*0.70710678118654752f));
  *(unsigned int*)(gTc + (size_t)j*INNER + ch) = pk2(g0, g1);
}

// ------- down-projection GEMM: 128j x 64c tile, BK=64, swizzled LDS ----------
__global__ __launch_bounds__(256) void k_down(const short* __restrict__ w2b,
                                              const float* __restrict__ b2,
                                              const short* __restrict__ gTc,
                                              const int* __restrict__ seg,
                                              float* __restrict__ Oc) {
  __shared__ alignas(16) short As[64*64];    // [c][k64], XOR-swizzled
  __shared__ alignas(16) short Bs[128*64];   // [j][k64], XOR-swizzled
  __shared__ float sb2[64];
  const int j0g = blockIdx.x << 7;
  if (j0g >= seg[24]) return;
  int e = 0;
  #pragma unroll
  for (int q = 0; q < NEXP; ++q)
    if (j0g >= seg[q*3] && j0g < seg[q*3+2]) e = q;
  const int c0 = blockIdx.y << 6;
  const short* A = w2b + (size_t)e*DIMC*INNER;
  const short* B = gTc + (size_t)j0g*INNER;
  const int t = threadIdx.x;
  const int wv = t >> 6, lane = t & 63;
  const int wc_ = (wv & 1) << 5;   // c-offset of wave
  const int wj  = (wv >> 1) << 6;  // j-offset of wave
  const int r15 = lane & 15, kg = lane >> 4;
  if (t < 64) sb2[t] = b2[e*DIMC + c0 + t];
  f32x4 acc[2][4] = {};
  for (int k0 = 0; k0 < INNER; k0 += 64) {
    __syncthreads();
    #pragma unroll
    for (int q = 0; q < 2; ++q) {              // A: 64 rows x 128B
      const int c = q*256 + t;
      const int row = c >> 3;
      const int kb = ((c & 7) << 4) ^ ((row & 7) << 4);
      gl2lds16(A + (size_t)(c0 + row)*INNER + k0 + (kb >> 1), (char*)As + c*16);
    }
    #pragma unroll
    for (int q = 0; q < 4; ++q) {              // B: 128 rows x 128B
      const int c = q*256 + t;
      const int row = c >> 3;
      const int kb = ((c & 7) << 4) ^ ((row & 7) << 4);
      gl2lds16(B + (size_t)row*INNER + k0 + (kb >> 1), (char*)Bs + c*16);
    }
    __syncthreads();
    #pragma unroll
    for (int ks = 0; ks < 2; ++ks) {
      bf16x8 af[2], bfr[4];
      #pragma unroll
      for (int mf = 0; mf < 2; ++mf) {
        const int row = wc_ + mf*16 + r15;
        const int kb = (ks*64 + kg*16) ^ ((row & 7) << 4);
        af[mf] = *(const bf16x8*)((const char*)As + row*128 + kb);
      }
      #pragma unroll
      for (int nf = 0; nf < 4; ++nf) {
        const int row = wj + nf*16 + r15;
        const int kb = (ks*64 + kg*16) ^ ((row & 7) << 4);
        bfr[nf] = *(const bf16x8*)((const char*)Bs + row*128 + kb);
      }
      #pragma unroll
      for (int mf = 0; mf < 2; ++mf)
        #pragma unroll
        for (int nf = 0; nf < 4; ++nf)
          acc[mf][nf] = __builtin_amdgcn_mfma_f32_16x16x32_bf16(af[mf], bfr[nf], acc[mf][nf], 0, 0, 0);
    }
  }
  #pragma unroll
  for (int mf = 0; mf < 2; ++mf) {
    const int ccl = wc_ + mf*16 + (kg << 2);
    #pragma unroll
    for (int nf = 0; nf < 4; ++nf) {
      const int jj = j0g + wj + nf*16 + r15;
      float4 v;
      v.x = acc[mf][nf][0] + sb2[ccl + 0];
      v.y = acc[mf][nf][1] + sb2[ccl + 1];
      v.z = acc[mf][nf][2] + sb2[ccl + 2];
      v.w = acc[mf][nf][3] + sb2[ccl + 3];
      *(float4*)(Oc + (size_t)jj*DIMC + c0 + ccl) = v;
    }
  }
}

// ---------------- final gather: out = w0*Oc[j0] + w1*Oc[j1] ------------------
__global__ __launch_bounds__(256) void k_gather(const float* __restrict__ Oc,
                                                const int* __restrict__ j0a,
                                                const int* __restrict__ j1a,
                                                const float2* __restrict__ w01,
                                                float* __restrict__ out) {
  const int t = threadIdx.x;
  const int n = blockIdx.x*256 + t;
  const int b = n >> 12, p = n & 4095;
  const int j0 = j0a[n], j1 = j1a[n];
  const float2 w = w01[n];
  const float4* r0 = (const float4*)(Oc + (size_t)j0*DIMC);
  const float4* r1 = (const float4*)(Oc + (size_t)j1*DIMC);
  float* ob = out + (size_t)b*DIMC*PPI + p;
  for (int cq = 0; cq < 48; ++cq) {
    float4 a = r0[cq], c = r1[cq];
    ob[(size_t)(cq*4 + 0)*PPI] = w.x*a.x + w.y*c.x;
    ob[(size_t)(cq*4 + 1)*PPI] = w.x*a.y + w.y*c.y;
    ob[(size_t)(cq*4 + 2)*PPI] = w.x*a.z + w.y*c.z;
    ob[(size_t)(cq*4 + 3)*PPI] = w.x*a.w + w.y*c.w;
  }
}

extern "C" void kernel_launch(void* const* d_in, const int* in_sizes, int n_in,
                              void* d_out, int out_size, void* d_ws, size_t ws_size,
                              hipStream_t stream) {
  (void)in_sizes; (void)n_in; (void)out_size;
  const float* x   = (const float*)d_in[0];
  const float* lng = (const float*)d_in[1];
  const float* lnb = (const float*)d_in[2];
  const float* w1  = (const float*)d_in[3];
  const float* b1  = (const float*)d_in[4];
  const float* dw  = (const float*)d_in[5];
  const float* bdw = (const float*)d_in[6];
  const float* w2  = (const float*)d_in[7];
  const float* b2  = (const float*)d_in[8];
  const float* wg  = (const float*)d_in[9];
  const float* bg  = (const float*)d_in[10];
  float* out = (float*)d_out;

  char* ws = (char*)d_ws;
  size_t off_ = 0;
  auto carve = [&](size_t bytes) -> void* {
    void* p = ws + off_;
    off_ = (off_ + bytes + 255) & ~(size_t)255;
    return p;
  };
  short* w1p  = (short*)carve((size_t)NEXP*INNER*DIMC*2);
  float* b1p  = (float*)carve((size_t)NEXP*INNER*4);
  short* w2b  = (short*)carve((size_t)NEXP*DIMC*INNER*2);
  short* nx   = (short*)carve((size_t)NPIX*DIMC*2);
  int*   e01  = (int*)carve((size_t)NPIX*4);
  float2* w01 = (float2*)carve((size_t)NPIX*8);
  int*   j0a  = (int*)carve((size_t)NPIX*4);
  int*   j1a  = (int*)carve((size_t)NPIX*4);
  int*   pix  = (int*)carve((size_t)MAXROWS*4);
  int*   slot = (int*)carve((size_t)NEXP*NPIX*4);
  int*   cnt  = (int*)carve(512*4);
  int*   offb = (int*)carve(512*4);
  int*   seg  = (int*)carve(32*4);
  short* gTc  = (short*)carve((size_t)MAXROWS*INNER*2);
  float* Oc   = (float*)carve((size_t)MAXROWS*DIMC*4);

  const size_t per_e = (size_t)INNER*NPIX*2;
  size_t rem = (ws_size > off_) ? (ws_size - off_) : 0;
  int ec = (int)(rem / per_e);
  if (ec > 4) ec = 4;
  if (ec < 1) ec = 1;
  short* hbuf = (short*)(ws + off_);

  k_prep_w1<<<dim3(INNER, NEXP), 192, 0, stream>>>(w1, b1, lng, lnb, w1p, b1p);
  k_prep_w2<<<dim3((NEXP*DIMC*INNER)/1024), 256, 0, stream>>>(w2, w2b, NEXP*DIMC*INNER);
  k_gate<<<dim3(NPIX/64), 256, 0, stream>>>(x, wg, bg, nx, e01, w01);
  k_route1<<<dim3(64), 256, 0, stream>>>(e01, cnt);
  k_route2<<<dim3(1), 64, 0, stream>>>(cnt, offb, seg);
  k_route3<<<dim3(64), 256, 0, stream>>>(e01, offb, slot, j0a, j1a, pix);
  k_padzero<<<dim3(NEXP), 256, 0, stream>>>(seg, gTc);

  for (int eb = 0; eb < NEXP; eb += ec) {
    int ne = (eb + ec <= NEXP) ? ec : (NEXP - eb);
    k_up<<<dim3(NPIX/128, INNER/128, ne), 256, 0, stream>>>(w1p, b1p, nx, hbuf, eb);
    k_dws<<<dim3(MAXROWS/8, INNER/64), 256, 0, stream>>>(hbuf, dw, bdw, pix, seg,
                                                         gTc, eb, ne);
  }
  k_down<<<dim3(MAXROWS/128, DIMC/64), 256, 0, stream>>>(w2b, b2, gTc, seg, Oc);
  k_gather<<<dim3(NPIX/256), 256, 0, stream>>>(Oc, j0a, j1a, w01, out);
}

// Round 9
// 226.660 us; speedup vs baseline: 1.2456x; 1.2456x over previous
//
#include <hip/hip_runtime.h>
#include <math.h>

#define DIMC 192
#define INNER 768
#define NEXP 8
#define NB 4
#define HH 64
#define WW 64
#define PPI 4096
#define NPIX 16384
#define MAXROWS 33792   // 264 * 128

typedef __attribute__((ext_vector_type(8))) short bf16x8;
typedef __attribute__((ext_vector_type(4))) float f32x4;

static __device__ __forceinline__ float bf2f(short s) {
  union { unsigned int u; float f; } v;
  v.u = ((unsigned int)(unsigned short)s) << 16;
  return v.f;
}
static __device__ __forceinline__ short f2bf(float f) {
  union { float f; unsigned int u; } v; v.f = f;
  unsigned int r = v.u + 0x7fffu + ((v.u >> 16) & 1u);
  return (short)(r >> 16);
}
static __device__ __forceinline__ unsigned int pk2(float a, float b) {
  return (unsigned int)(unsigned short)f2bf(a)
       | ((unsigned int)(unsigned short)f2bf(b) << 16);
}
static __device__ __forceinline__ void gl2lds16(const void* g, void* l) {
  __builtin_amdgcn_global_load_lds(
      (const __attribute__((address_space(1))) void*)g,
      (__attribute__((address_space(3))) void*)l, 16, 0, 0);
}

// ---------------- prep: fold LN gamma/beta into W1/b1, cast to bf16 ----------
__global__ __launch_bounds__(192) void k_prep_w1(const float* __restrict__ w1,
                                                 const float* __restrict__ b1,
                                                 const float* __restrict__ lng,
                                                 const float* __restrict__ lnb,
                                                 short* __restrict__ w1p,
                                                 float* __restrict__ b1p) {
  const int i = blockIdx.x;
  const int e = blockIdx.y;
  const int c = threadIdx.x;
  const size_t base = ((size_t)e*INNER + i)*DIMC;
  float w = w1[base + c];
  float g = lng[e*DIMC + c];
  float bb = lnb[e*DIMC + c];
  w1p[base + c] = f2bf(w * g);
  float r = w * bb;
  #pragma unroll
  for (int off = 32; off >= 1; off >>= 1) r += __shfl_down(r, off);
  __shared__ float part[3];
  const int lane = threadIdx.x & 63, wv = threadIdx.x >> 6;
  if (lane == 0) part[wv] = r;
  __syncthreads();
  if (threadIdx.x == 0)
    b1p[e*INNER + i] = b1[e*INNER + i] + part[0] + part[1] + part[2];
}

__global__ __launch_bounds__(256) void k_prep_w2(const float* __restrict__ w2,
                                                 short* __restrict__ w2b, int n) {
  int idx = (blockIdx.x*256 + threadIdx.x)*4;
  if (idx + 3 < n) {
    float4 v = *(const float4*)(w2 + idx);
    short4 o; o.x = f2bf(v.x); o.y = f2bf(v.y); o.z = f2bf(v.z); o.w = f2bf(v.w);
    *(short4*)(w2b + idx) = o;
  } else {
    for (int k = idx; k < n; ++k) w2b[k] = f2bf(w2[k]);
  }
}

// ---------------- gate + layernorm -> nx, (e0,e1), (w0,w1) -------------------
__global__ __launch_bounds__(256) void k_gate(const float* __restrict__ x,
                                              const float* __restrict__ wg,
                                              const float* __restrict__ bg,
                                              short* __restrict__ nx,
                                              int* __restrict__ e01,
                                              float2* __restrict__ w01) {
  __shared__ float swg[NEXP][DIMC];
  __shared__ float sbg[NEXP];
  __shared__ float red[10][4][64];
  __shared__ float smr[2][64];
  const int t = threadIdx.x;
  for (int k = t; k < NEXP*DIMC; k += 256) swg[k/DIMC][k%DIMC] = wg[k];
  if (t < NEXP) sbg[t] = bg[t];
  __syncthreads();
  const int n0 = blockIdx.x * 64;
  const int b = n0 >> 12;
  const int p0 = n0 & 4095;
  const int l = t & 63, w = t >> 6;
  const float* xp = x + (size_t)b*DIMC*PPI + p0 + l;
  float xr[48];
  float sum = 0.f, ssq = 0.f;
  float lg[NEXP] = {0,0,0,0,0,0,0,0};
  #pragma unroll
  for (int k = 0; k < 48; ++k) {
    const int c = w*48 + k;
    float xv = xp[(size_t)c*PPI];
    xr[k] = xv;
    sum += xv; ssq += xv*xv;
    #pragma unroll
    for (int e = 0; e < NEXP; ++e) lg[e] += xv * swg[e][c];
  }
  red[0][w][l] = sum;
  red[1][w][l] = ssq;
  #pragma unroll
  for (int e = 0; e < NEXP; ++e) red[2+e][w][l] = lg[e];
  __syncthreads();
  if (t < 64) {
    float ts = red[0][0][l] + red[0][1][l] + red[0][2][l] + red[0][3][l];
    float tq = red[1][0][l] + red[1][1][l] + red[1][2][l] + red[1][3][l];
    float lgt[NEXP];
    #pragma unroll
    for (int e = 0; e < NEXP; ++e)
      lgt[e] = red[2+e][0][l] + red[2+e][1][l] + red[2+e][2][l] + red[2+e][3][l] + sbg[e];
    const float mean = ts * (1.0f/DIMC);
    const float var  = tq * (1.0f/DIMC) - mean*mean;
    const float rstd = rsqrtf(var + 1e-5f);
    smr[0][l] = mean; smr[1][l] = rstd;
    int e0 = 0; float l0 = lgt[0];
    #pragma unroll
    for (int e = 1; e < NEXP; ++e) if (lgt[e] > l0) { l0 = lgt[e]; e0 = e; }
    int e1 = -1; float l1 = -1e30f;
    #pragma unroll
    for (int e = 0; e < NEXP; ++e) if (e != e0 && lgt[e] > l1) { l1 = lgt[e]; e1 = e; }
    const float ex = expf(l1 - l0);
    const float w0 = 1.0f/(1.0f + ex);
    const float w1v = ex * w0;
    e01[n0 + l] = e0 | (e1 << 8);
    w01[n0 + l] = make_float2(w0, w1v);
  }
  __syncthreads();
  const float mean = smr[0][l], rstd = smr[1][l];
  short* nrow = nx + (size_t)(n0 + l)*DIMC + w*48;
  #pragma unroll
  for (int q = 0; q < 6; ++q) {
    bf16x8 v;
    #pragma unroll
    for (int j = 0; j < 8; ++j)
      v[j] = f2bf((xr[q*8 + j] - mean) * rstd);
    *(bf16x8*)(nrow + q*8) = v;
  }
}

// ---------------- routing pass 1: per-(expert, 256px-block) counts -----------
__global__ __launch_bounds__(256) void k_route1(const int* __restrict__ e01,
                                                int* __restrict__ cnt) {
  __shared__ int wc[NEXP][4];
  const int t = threadIdx.x;
  const int n = blockIdx.x*256 + t;
  const int ee = e01[n];
  const int e0 = ee & 0xff, e1 = (ee >> 8) & 0xff;
  const int lane = t & 63, wv = t >> 6;
  #pragma unroll
  for (int e = 0; e < NEXP; ++e) {
    unsigned long long m = __ballot(e0 == e || e1 == e);
    if (lane == 0) wc[e][wv] = __popcll(m);
  }
  __syncthreads();
  if (t < NEXP) cnt[t*64 + blockIdx.x] = wc[t][0] + wc[t][1] + wc[t][2] + wc[t][3];
}

// ---------------- routing pass 2: serial scan -> offsets, segments -----------
__global__ void k_route2(const int* __restrict__ cnt, int* __restrict__ off,
                         int* __restrict__ seg) {
  if (threadIdx.x != 0 || blockIdx.x != 0) return;
  int start = 0;
  for (int e = 0; e < NEXP; ++e) {
    int run = start;
    for (int b = 0; b < 64; ++b) { off[e*64 + b] = run; run += cnt[e*64 + b]; }
    int m = run - start;
    int pad = (m + 127) & ~127;
    seg[e*3 + 0] = start;
    seg[e*3 + 1] = m;
    seg[e*3 + 2] = start + pad;
    start += pad;
  }
  seg[24] = start;  // total padded rows
}

// -------- routing pass 3: slots (dense->compact), j0/j1, slot->pixel --------
__global__ __launch_bounds__(256) void k_route3(const int* __restrict__ e01,
                                                const int* __restrict__ off,
                                                int* __restrict__ slot,
                                                int* __restrict__ j0a,
                                                int* __restrict__ j1a,
                                                int* __restrict__ pix) {
  __shared__ int wc[NEXP][4];
  const int t = threadIdx.x;
  const int n = blockIdx.x*256 + t;
  const int ee = e01[n];
  const int e0 = ee & 0xff, e1 = (ee >> 8) & 0xff;
  const int lane = t & 63, wv = t >> 6;
  unsigned long long masks[NEXP];
  #pragma unroll
  for (int e = 0; e < NEXP; ++e) {
    unsigned long long m = __ballot(e0 == e || e1 == e);
    if (lane == 0) wc[e][wv] = __popcll(m);
    masks[e] = m;
  }
  __syncthreads();
  int j0 = 0, j1 = 0;
  #pragma unroll
  for (int e = 0; e < NEXP; ++e) {
    int base = off[e*64 + blockIdx.x];
    #pragma unroll
    for (int w = 0; w < 4; ++w) if (w < wv) base += wc[e][w];
    int rank = __popcll(masks[e] & ((1ull << lane) - 1ull));
    bool sel = (e0 == e || e1 == e);
    int j = base + rank;
    slot[(size_t)e*NPIX + n] = sel ? j : -1;
    if (sel) pix[j] = n;
    if (e == e0) j0 = j;
    if (e == e1) j1 = j;
  }
  j0a[n] = j0; j1a[n] = j1;
}

// ---------------- zero gTc padding rows --------------------------------------
__global__ __launch_bounds__(256) void k_padzero(const int* __restrict__ seg,
                                                 short* __restrict__ gTc) {
  const int e = blockIdx.x;
  const int start = seg[e*3], m = seg[e*3+1], pend = seg[e*3+2];
  const size_t base = (size_t)(start + m) * INNER;
  const size_t n = (size_t)(pend - start - m) * INNER;
  for (size_t i = threadIdx.x; i < n; i += 256) gTc[base + i] = 0;
}

// ------- up-projection GEMM: 128x128, BK=64, XOR-swizzled LDS;
// ------- epilogue: LDS transpose -> hT[n][768] coalesced 16B stores ----------
__global__ __launch_bounds__(256) void k_up(const short* __restrict__ w1p,
                                            const float* __restrict__ b1p,
                                            const short* __restrict__ nx,
                                            short* __restrict__ hbuf, int eb) {
  __shared__ alignas(16) short smemU[128*136];   // As|Bs during GEMM, TT after
  short* As = smemU;
  short* Bs = smemU + 128*64;
  const int el = blockIdx.z;
  const int e = eb + el;
  const short* A = w1p + (size_t)e*INNER*DIMC;
  short* H = hbuf + (size_t)el*NPIX*INNER;      // hT layout [n][768]
  const int n0 = blockIdx.x << 7;
  const int i0 = blockIdx.y << 7;
  const int t = threadIdx.x;
  const int wv = t >> 6, lane = t & 63;
  const int wm = (wv & 1) << 6;
  const int wn = (wv >> 1) << 6;
  const int r15 = lane & 15, kg = lane >> 4;
  f32x4 acc[4][4] = {};
  for (int k0 = 0; k0 < DIMC; k0 += 64) {
    __syncthreads();
    #pragma unroll
    for (int q = 0; q < 4; ++q) {
      const int c = q*256 + t;
      const int row = c >> 3;
      const int kb = ((c & 7) << 4) ^ ((row & 7) << 4);   // pre-swizzled source
      gl2lds16(A + (size_t)(i0 + row)*DIMC + k0 + (kb >> 1), (char*)As + c*16);
      gl2lds16(nx + (size_t)(n0 + row)*DIMC + k0 + (kb >> 1), (char*)Bs + c*16);
    }
    __syncthreads();
    #pragma unroll
    for (int ks = 0; ks < 2; ++ks) {
      bf16x8 af[4], bfr[4];
      #pragma unroll
      for (int mf = 0; mf < 4; ++mf) {
        const int row = wm + mf*16 + r15;
        const int kb = (ks*64 + kg*16) ^ ((row & 7) << 4);
        af[mf] = *(const bf16x8*)((const char*)As + row*128 + kb);
      }
      #pragma unroll
      for (int nf = 0; nf < 4; ++nf) {
        const int row = wn + nf*16 + r15;
        const int kb = (ks*64 + kg*16) ^ ((row & 7) << 4);
        bfr[nf] = *(const bf16x8*)((const char*)Bs + row*128 + kb);
      }
      #pragma unroll
      for (int mf = 0; mf < 4; ++mf)
        #pragma unroll
        for (int nf = 0; nf < 4; ++nf)
          acc[mf][nf] = __builtin_amdgcn_mfma_f32_16x16x32_bf16(af[mf], bfr[nf], acc[mf][nf], 0, 0, 0);
    }
  }
  // epilogue: acc(+bias) -> TT[n_l][i_l] (stride 136 shorts, 16B-aligned rows)
  __syncthreads();
  unsigned int* TT32 = (unsigned int*)smemU;
  const float* b1e = b1p + e*INNER + i0;
  #pragma unroll
  for (int mf = 0; mf < 4; ++mf) {
    const int ib = wm + mf*16 + (kg << 2);
    float bias[4];
    #pragma unroll
    for (int r = 0; r < 4; ++r) bias[r] = b1e[ib + r];
    #pragma unroll
    for (int nf = 0; nf < 4; ++nf) {
      const int nl = wn + nf*16 + r15;
      TT32[nl*68 + (ib >> 1)]     = pk2(acc[mf][nf][0] + bias[0], acc[mf][nf][1] + bias[1]);
      TT32[nl*68 + (ib >> 1) + 1] = pk2(acc[mf][nf][2] + bias[2], acc[mf][nf][3] + bias[3]);
    }
  }
  __syncthreads();
  const short* TT = smemU;
  #pragma unroll
  for (int s = 0; s < 8; ++s) {
    const int idx = (s << 8) + t;
    const int nl = idx >> 4, cg = idx & 15;
    bf16x8 v = *(const bf16x8*)(TT + nl*136 + cg*8);
    *(bf16x8*)(H + (size_t)(n0 + nl)*INNER + i0 + cg*8) = v;
  }
}

// ------- sparse depthwise 3x3 + GELU; thread = 4 slots x 8 channels ----------
// weights in 72 registers (288B streaming load); 9 x 16B tap loads per slot
__global__ __launch_bounds__(256) void k_dws(const short* __restrict__ hbuf,
                                             const float* __restrict__ dw,
                                             const float* __restrict__ bdw,
                                             const int* __restrict__ pix,
                                             const int* __restrict__ seg,
                                             short* __restrict__ gTc,
                                             int eb, int ne) {
  const int j0 = blockIdx.x << 5;     // 32 slots per block (32 | 128 -> one expert)
  if (j0 >= seg[24]) return;
  int e = 0;
  #pragma unroll
  for (int q = 0; q < NEXP; ++q)
    if (j0 >= seg[q*3] && j0 < seg[q*3+2]) e = q;
  if (e < eb || e >= eb + ne) return;
  const int jend = seg[e*3] + seg[e*3+1];
  const int t = threadIdx.x;
  const int oct = t & 31;             // 32 octets = 256 channels per grid.y
  const int sq = t >> 5;              // 8 slot-quads
  const int ch = (blockIdx.y << 8) + (oct << 3);
  const short* hb = hbuf + (size_t)(e - eb)*NPIX*INNER;
  float wf[72];
  {
    const float4* wp = (const float4*)(dw + ((size_t)e*INNER + ch)*9);
    #pragma unroll
    for (int q = 0; q < 18; ++q) {
      const float4 v4 = wp[q];
      wf[q*4+0] = v4.x; wf[q*4+1] = v4.y; wf[q*4+2] = v4.z; wf[q*4+3] = v4.w;
    }
  }
  float bias[8];
  {
    const float4* bp = (const float4*)(bdw + (size_t)e*INNER + ch);
    const float4 b0 = bp[0], b1 = bp[1];
    bias[0]=b0.x; bias[1]=b0.y; bias[2]=b0.z; bias[3]=b0.w;
    bias[4]=b1.x; bias[5]=b1.y; bias[6]=b1.z; bias[7]=b1.w;
  }
  #pragma unroll
  for (int s = 0; s < 4; ++s) {
    const int j = j0 + (sq << 2) + s;
    if (j >= jend) continue;          // padding slot (gTc pre-zeroed)
    const int n = pix[j];
    const int p = n & 4095, y = p >> 6, x = p & 63;
    bf16x8 v[9];
    #pragma unroll
    for (int dy = -1; dy <= 1; ++dy)
      #pragma unroll
      for (int dx = -1; dx <= 1; ++dx) {
        bf16x8 z = {0,0,0,0,0,0,0,0};
        if ((unsigned)(y + dy) < 64u && (unsigned)(x + dx) < 64u)
          z = *(const bf16x8*)(hb + (size_t)(n + dy*64 + dx)*INNER + ch);
        v[(dy+1)*3 + dx + 1] = z;
      }
    bf16x8 vo;
    #pragma unroll
    for (int c = 0; c < 8; ++c) {
      float a = bias[c];
      #pragma unroll
      for (int q = 0; q < 9; ++q)
        a += wf[c*9 + q] * bf2f(v[q][c]);
      const float g = 0.5f*a*(1.0f + erff(a*0.70710678118654752f));
      vo[c] = f2bf(g);
    }
    *(bf16x8*)(gTc + (size_t)j*INNER + ch) = vo;
  }
}

// ------- down-projection GEMM: 128j x 64c tile, BK=64, swizzled LDS ----------
__global__ __launch_bounds__(256) void k_down(const short* __restrict__ w2b,
                                              const float* __restrict__ b2,
                                              const short* __restrict__ gTc,
                                              const int* __restrict__ seg,
                                              float* __restrict__ Oc) {
  __shared__ alignas(16) short As[64*64];    // [c][k64], XOR-swizzled
  __shared__ alignas(16) short Bs[128*64];   // [j][k64], XOR-swizzled
  __shared__ float sb2[64];
  const int j0g = blockIdx.x << 7;
  if (j0g >= seg[24]) return;
  int e = 0;
  #pragma unroll
  for (int q = 0; q < NEXP; ++q)
    if (j0g >= seg[q*3] && j0g < seg[q*3+2]) e = q;
  const int c0 = blockIdx.y << 6;
  const short* A = w2b + (size_t)e*DIMC*INNER;
  const short* B = gTc + (size_t)j0g*INNER;
  const int t = threadIdx.x;
  const int wv = t >> 6, lane = t & 63;
  const int wc_ = (wv & 1) << 5;   // c-offset of wave
  const int wj  = (wv >> 1) << 6;  // j-offset of wave
  const int r15 = lane & 15, kg = lane >> 4;
  if (t < 64) sb2[t] = b2[e*DIMC + c0 + t];
  f32x4 acc[2][4] = {};
  for (int k0 = 0; k0 < INNER; k0 += 64) {
    __syncthreads();
    #pragma unroll
    for (int q = 0; q < 2; ++q) {              // A: 64 rows x 128B
      const int c = q*256 + t;
      const int row = c >> 3;
      const int kb = ((c & 7) << 4) ^ ((row & 7) << 4);
      gl2lds16(A + (size_t)(c0 + row)*INNER + k0 + (kb >> 1), (char*)As + c*16);
    }
    #pragma unroll
    for (int q = 0; q < 4; ++q) {              // B: 128 rows x 128B
      const int c = q*256 + t;
      const int row = c >> 3;
      const int kb = ((c & 7) << 4) ^ ((row & 7) << 4);
      gl2lds16(B + (size_t)row*INNER + k0 + (kb >> 1), (char*)Bs + c*16);
    }
    __syncthreads();
    #pragma unroll
    for (int ks = 0; ks < 2; ++ks) {
      bf16x8 af[2], bfr[4];
      #pragma unroll
      for (int mf = 0; mf < 2; ++mf) {
        const int row = wc_ + mf*16 + r15;
        const int kb = (ks*64 + kg*16) ^ ((row & 7) << 4);
        af[mf] = *(const bf16x8*)((const char*)As + row*128 + kb);
      }
      #pragma unroll
      for (int nf = 0; nf < 4; ++nf) {
        const int row = wj + nf*16 + r15;
        const int kb = (ks*64 + kg*16) ^ ((row & 7) << 4);
        bfr[nf] = *(const bf16x8*)((const char*)Bs + row*128 + kb);
      }
      #pragma unroll
      for (int mf = 0; mf < 2; ++mf)
        #pragma unroll
        for (int nf = 0; nf < 4; ++nf)
          acc[mf][nf] = __builtin_amdgcn_mfma_f32_16x16x32_bf16(af[mf], bfr[nf], acc[mf][nf], 0, 0, 0);
    }
  }
  #pragma unroll
  for (int mf = 0; mf < 2; ++mf) {
    const int ccl = wc_ + mf*16 + (kg << 2);
    #pragma unroll
    for (int nf = 0; nf < 4; ++nf) {
      const int jj = j0g + wj + nf*16 + r15;
      float4 v;
      v.x = acc[mf][nf][0] + sb2[ccl + 0];
      v.y = acc[mf][nf][1] + sb2[ccl + 1];
      v.z = acc[mf][nf][2] + sb2[ccl + 2];
      v.w = acc[mf][nf][3] + sb2[ccl + 3];
      *(float4*)(Oc + (size_t)jj*DIMC + c0 + ccl) = v;
    }
  }
}

// ---------------- final gather: out = w0*Oc[j0] + w1*Oc[j1] ------------------
__global__ __launch_bounds__(256) void k_gather(const float* __restrict__ Oc,
                                                const int* __restrict__ j0a,
                                                const int* __restrict__ j1a,
                                                const float2* __restrict__ w01,
                                                float* __restrict__ out) {
  const int t = threadIdx.x;
  const int n = blockIdx.x*256 + t;
  const int b = n >> 12, p = n & 4095;
  const int j0 = j0a[n], j1 = j1a[n];
  const float2 w = w01[n];
  const float4* r0 = (const float4*)(Oc + (size_t)j0*DIMC);
  const float4* r1 = (const float4*)(Oc + (size_t)j1*DIMC);
  float* ob = out + (size_t)b*DIMC*PPI + p;
  for (int cq = 0; cq < 48; ++cq) {
    float4 a = r0[cq], c = r1[cq];
    ob[(size_t)(cq*4 + 0)*PPI] = w.x*a.x + w.y*c.x;
    ob[(size_t)(cq*4 + 1)*PPI] = w.x*a.y + w.y*c.y;
    ob[(size_t)(cq*4 + 2)*PPI] = w.x*a.z + w.y*c.z;
    ob[(size_t)(cq*4 + 3)*PPI] = w.x*a.w + w.y*c.w;
  }
}

extern "C" void kernel_launch(void* const* d_in, const int* in_sizes, int n_in,
                              void* d_out, int out_size, void* d_ws, size_t ws_size,
                              hipStream_t stream) {
  (void)in_sizes; (void)n_in; (void)out_size;
  const float* x   = (const float*)d_in[0];
  const float* lng = (const float*)d_in[1];
  const float* lnb = (const float*)d_in[2];
  const float* w1  = (const float*)d_in[3];
  const float* b1  = (const float*)d_in[4];
  const float* dw  = (const float*)d_in[5];
  const float* bdw = (const float*)d_in[6];
  const float* w2  = (const float*)d_in[7];
  const float* b2  = (const float*)d_in[8];
  const float* wg  = (const float*)d_in[9];
  const float* bg  = (const float*)d_in[10];
  float* out = (float*)d_out;

  char* ws = (char*)d_ws;
  size_t off_ = 0;
  auto carve = [&](size_t bytes) -> void* {
    void* p = ws + off_;
    off_ = (off_ + bytes + 255) & ~(size_t)255;
    return p;
  };
  short* w1p  = (short*)carve((size_t)NEXP*INNER*DIMC*2);
  float* b1p  = (float*)carve((size_t)NEXP*INNER*4);
  short* w2b  = (short*)carve((size_t)NEXP*DIMC*INNER*2);
  short* nx   = (short*)carve((size_t)NPIX*DIMC*2);
  int*   e01  = (int*)carve((size_t)NPIX*4);
  float2* w01 = (float2*)carve((size_t)NPIX*8);
  int*   j0a  = (int*)carve((size_t)NPIX*4);
  int*   j1a  = (int*)carve((size_t)NPIX*4);
  int*   pix  = (int*)carve((size_t)MAXROWS*4);
  int*   slot = (int*)carve((size_t)NEXP*NPIX*4);
  int*   cnt  = (int*)carve(512*4);
  int*   offb = (int*)carve(512*4);
  int*   seg  = (int*)carve(32*4);
  short* gTc  = (short*)carve((size_t)MAXROWS*INNER*2);
  float* Oc   = (float*)carve((size_t)MAXROWS*DIMC*4);

  const size_t per_e = (size_t)INNER*NPIX*2;
  size_t rem = (ws_size > off_) ? (ws_size - off_) : 0;
  int ec = (int)(rem / per_e);
  if (ec > NEXP) ec = NEXP;
  if (ec < 1) ec = 1;
  short* hbuf = (short*)(ws + off_);

  k_prep_w1<<<dim3(INNER, NEXP), 192, 0, stream>>>(w1, b1, lng, lnb, w1p, b1p);
  k_prep_w2<<<dim3((NEXP*DIMC*INNER)/1024), 256, 0, stream>>>(w2, w2b, NEXP*DIMC*INNER);
  k_gate<<<dim3(NPIX/64), 256, 0, stream>>>(x, wg, bg, nx, e01, w01);
  k_route1<<<dim3(64), 256, 0, stream>>>(e01, cnt);
  k_route2<<<dim3(1), 64, 0, stream>>>(cnt, offb, seg);
  k_route3<<<dim3(64), 256, 0, stream>>>(e01, offb, slot, j0a, j1a, pix);
  k_padzero<<<dim3(NEXP), 256, 0, stream>>>(seg, gTc);

  for (int eb = 0; eb < NEXP; eb += ec) {
    int ne = (eb + ec <= NEXP) ? ec : (NEXP - eb);
    k_up<<<dim3(NPIX/128, INNER/128, ne), 256, 0, stream>>>(w1p, b1p, nx, hbuf, eb);
    k_dws<<<dim3(MAXROWS/32, 3), 256, 0, stream>>>(hbuf, dw, bdw, pix, seg,
                                                   gTc, eb, ne);
  }
  k_down<<<dim3(MAXROWS/128, DIMC/64), 256, 0, stream>>>(w2b, b2, gTc, seg, Oc);
  k_gather<<<dim3(NPIX/256), 256, 0, stream>>>(Oc, j0a, j1a, w01, out);
}